// Round 1
// baseline (359.241 us; speedup 1.0000x reference)
//
#include <hip/hip_runtime.h>
#include <hip/hip_bf16.h>
#include <math.h>

#define Bq 8
#define Tq 2048
#define Dq 2048
#define Rq 4
#define Mq (Bq*Tq)      // 16384
#define NC 16           // scan chunks
#define CL (Tq/NC)      // 128 timesteps per chunk

typedef __attribute__((ext_vector_type(8))) short bf16x8;
typedef __attribute__((ext_vector_type(4))) float f32x4;
typedef __attribute__((ext_vector_type(4))) unsigned short us4;

__device__ __forceinline__ unsigned short f2bf(float x) {
    unsigned int u = __float_as_uint(x);
    unsigned int r = (u + 0x7fffu + ((u >> 16) & 1u)) >> 16;   // RNE
    return (unsigned short)r;
}

// ---------------- K0: convert u, gate_w to bf16; build aa / aa^CL tables ----
__global__ __launch_bounds__(256) void k0_convert(
    const float* __restrict__ u, const float* __restrict__ gw,
    const float* __restrict__ a,
    unsigned short* __restrict__ ubf, unsigned short* __restrict__ wbf,
    float* __restrict__ aat, float* __restrict__ aaLt)
{
    const long long uN4 = (long long)Mq * Dq / 4;   // 8388608
    const long long wN4 = (long long)Dq * Dq / 4;   // 1048576
    long long gid = (long long)blockIdx.x * blockDim.x + threadIdx.x;
    if (gid < Dq) {
        float aa = tanhf(a[gid]);
        aat[gid] = aa;
        aaLt[gid] = exp2f((float)CL * log2f(aa));
    }
    long long stride = (long long)gridDim.x * blockDim.x;
    for (long long i = gid; i < uN4 + wN4; i += stride) {
        const float4* src; unsigned short* dst; long long j;
        if (i < uN4) { src = (const float4*)u;  dst = ubf; j = i; }
        else         { src = (const float4*)gw; dst = wbf; j = i - uN4; }
        float4 v = src[j];
        us4 p;
        p.x = f2bf(v.x); p.y = f2bf(v.y); p.z = f2bf(v.z); p.w = f2bf(v.w);
        *(us4*)(dst + j * 4) = p;
    }
}

// ---------------- K1: bf16 MFMA GEMM (m97 structure) + sigmoid epilogue -----
#define BMt 128
#define BNt 128
#define BKt 32

__global__ __launch_bounds__(256) void k1_gemm(
    const unsigned short* __restrict__ Abf,   // u   [M][K] bf16
    const unsigned short* __restrict__ Bbf,   // gw  [N][K] bf16 (B^T layout)
    const float* __restrict__ u,              // u   [M][D] f32
    const float* __restrict__ gate_b,         // [D]
    float* __restrict__ ug)                   // out: u_g [M][D] f32 (= d_out)
{
    __shared__ unsigned short As[BMt * BKt];
    __shared__ unsigned short Bs[BNt * BKt];
    const int tid  = threadIdx.x;
    const int wave = tid >> 6, lane = tid & 63;
    const int tm = blockIdx.y * BMt;          // gridDim.y = 128
    const int tn = blockIdx.x * BNt;          // gridDim.x = 16
    const int wr = wave >> 1, wc = wave & 1;  // wave quadrant (64x64)

    f32x4 acc[4][4] = {};

    const int lrow = lane >> 2;               // 0..15 row-in-chunk
    const int lcol = (lane & 3) * 8;          // bf16 col offset (k)
    const long long K = Dq;

    for (int kt = 0; kt < Dq; kt += BKt) {
        __syncthreads();
        // stage A tile: 128x32 bf16 = 8 KB = 8 wave-chunks of 1024 B
#pragma unroll
        for (int i = 0; i < 2; ++i) {
            int chunk = wave + i * 4;
            int row = chunk * 16 + lrow;
            const unsigned short* g = Abf + (long long)(tm + row) * K + kt + lcol;
            __builtin_amdgcn_global_load_lds(
                (const __attribute__((address_space(1))) void*)g,
                (__attribute__((address_space(3))) void*)(As + chunk * 512),
                16, 0, 0);
        }
#pragma unroll
        for (int i = 0; i < 2; ++i) {
            int chunk = wave + i * 4;
            int row = chunk * 16 + lrow;
            const unsigned short* g = Bbf + (long long)(tn + row) * K + kt + lcol;
            __builtin_amdgcn_global_load_lds(
                (const __attribute__((address_space(1))) void*)g,
                (__attribute__((address_space(3))) void*)(Bs + chunk * 512),
                16, 0, 0);
        }
        __syncthreads();

        const int kb = (lane >> 4) * 8;       // k offset 0/8/16/24
        const int rr = lane & 15;
        bf16x8 af[4], bfr[4];
#pragma unroll
        for (int f = 0; f < 4; ++f)
            af[f] = *(const bf16x8*)&As[(wr * 64 + f * 16 + rr) * BKt + kb];
#pragma unroll
        for (int f = 0; f < 4; ++f)
            bfr[f] = *(const bf16x8*)&Bs[(wc * 64 + f * 16 + rr) * BKt + kb];
#pragma unroll
        for (int fm = 0; fm < 4; ++fm)
#pragma unroll
            for (int fn = 0; fn < 4; ++fn)
                acc[fm][fn] = __builtin_amdgcn_mfma_f32_16x16x32_bf16(
                    af[fm], bfr[fn], acc[fm][fn], 0, 0, 0);
    }

    // epilogue: u_g = u * sigmoid(logit + gate_b)
    const int rr = lane & 15, rg = lane >> 4;
#pragma unroll
    for (int fm = 0; fm < 4; ++fm) {
#pragma unroll
        for (int fn = 0; fn < 4; ++fn) {
            int col = tn + wc * 64 + fn * 16 + rr;
            float gb = gate_b[col];
#pragma unroll
            for (int j = 0; j < 4; ++j) {
                int row = tm + wr * 64 + fm * 16 + rg * 4 + j;
                long long idx = (long long)row * Dq + col;
                float logit = acc[fm][fn][j] + gb;
                float s = 1.0f / (1.0f + __expf(-logit));
                ug[idx] = u[idx] * s;
            }
        }
    }
}

// ---------------- K2: scan pass A — per-chunk local scan + partial sums -----
__global__ __launch_bounds__(128) void k2_scanA(
    const float* __restrict__ ug, const float* __restrict__ aat,
    const float* __restrict__ bvec,
    float* __restrict__ psum, float* __restrict__ carry)
{
    // grid: x = D/512 (4), y = NC (16), z = B (8); 128 thr, 4 d per thread
    const int d0 = blockIdx.x * 512 + threadIdx.x * 4;
    const int ck = blockIdx.y, bb = blockIdx.z;
    f32x4 aa = *(const f32x4*)&aat[d0];
    f32x4 bv = *(const f32x4*)&bvec[d0];
    f32x4 s = {0.f, 0.f, 0.f, 0.f}, sum = {0.f, 0.f, 0.f, 0.f};
    const float* base = ug + ((long long)bb * Tq + (long long)ck * CL) * Dq + d0;
    for (int t = 0; t < CL; ++t) {
        f32x4 x = *(const f32x4*)(base + (long long)t * Dq);
        sum += x;
        s = aa * s + bv * x;
    }
    long long ci = ((long long)bb * NC + ck) * Dq + d0;
    *(f32x4*)&psum[ci]  = sum;
    *(f32x4*)&carry[ci] = s;
}

// ---------------- K3: mean -> rank-4 projection -> d_eff --------------------
__global__ __launch_bounds__(256) void k3_deff(
    const float* __restrict__ psum, const float* __restrict__ dvec,
    const float* __restrict__ dlru, const float* __restrict__ dlrv,
    float* __restrict__ deff)
{
    const int bb = blockIdx.x, tid = threadIdx.x;
    __shared__ float red[4][256];
    __shared__ float proj[4];
    float pr[4] = {0.f, 0.f, 0.f, 0.f};
    for (int i = 0; i < Dq / 256; ++i) {
        int dd = tid + i * 256;
        float m = 0.f;
        for (int k = 0; k < NC; ++k) m += psum[((long long)bb * NC + k) * Dq + dd];
        m *= (1.0f / (float)Tq);
#pragma unroll
        for (int r = 0; r < 4; ++r) pr[r] += m * dlru[dd * Rq + r];
    }
#pragma unroll
    for (int r = 0; r < 4; ++r) red[r][tid] = pr[r];
    __syncthreads();
    for (int off = 128; off > 0; off >>= 1) {
        if (tid < off)
#pragma unroll
            for (int r = 0; r < 4; ++r) red[r][tid] += red[r][tid + off];
        __syncthreads();
    }
    if (tid < 4) proj[tid] = red[tid][0] * 0.25f;   // / max(1, R)
    __syncthreads();
    float p0 = proj[0], p1 = proj[1], p2 = proj[2], p3 = proj[3];
    for (int i = 0; i < Dq / 256; ++i) {
        int e = tid + i * 256;
        float v = dvec[e] + p0 * dlrv[0 * Dq + e] + p1 * dlrv[1 * Dq + e]
                          + p2 * dlrv[2 * Dq + e] + p3 * dlrv[3 * Dq + e];
        deff[(long long)bb * Dq + e] = v;
    }
}

// ---------------- K4: scan pass C — combine carries, rescan, write y --------
__global__ __launch_bounds__(128) void k4_scanC(
    float* __restrict__ ug,                   // in: u_g, out: y (in-place)
    const float* __restrict__ aat, const float* __restrict__ aaLt,
    const float* __restrict__ bvec, const float* __restrict__ cvec,
    const float* __restrict__ deff, const float* __restrict__ carry)
{
    const int d0 = blockIdx.x * 512 + threadIdx.x * 4;
    const int ck = blockIdx.y, bb = blockIdx.z;
    f32x4 aa  = *(const f32x4*)&aat[d0];
    f32x4 aaL = *(const f32x4*)&aaLt[d0];
    f32x4 bv  = *(const f32x4*)&bvec[d0];
    f32x4 cv  = *(const f32x4*)&cvec[d0];
    f32x4 de  = *(const f32x4*)&deff[(long long)bb * Dq + d0];
    f32x4 s = {0.f, 0.f, 0.f, 0.f};
    for (int j = 0; j < ck; ++j) {            // combine preceding chunk carries
        f32x4 cj = *(const f32x4*)&carry[((long long)bb * NC + j) * Dq + d0];
        s = aaL * s + cj;
    }
    float* base = ug + ((long long)bb * Tq + (long long)ck * CL) * Dq + d0;
    for (int t = 0; t < CL; ++t) {
        f32x4 x = *(const f32x4*)(base + (long long)t * Dq);
        s = aa * s + bv * x;
        f32x4 y = cv * s + de * x;
        *(f32x4*)(base + (long long)t * Dq) = y;
    }
}

extern "C" void kernel_launch(void* const* d_in, const int* in_sizes, int n_in,
                              void* d_out, int out_size, void* d_ws, size_t ws_size,
                              hipStream_t stream)
{
    const float* u    = (const float*)d_in[0];
    const float* a    = (const float*)d_in[1];
    const float* b    = (const float*)d_in[2];
    const float* c    = (const float*)d_in[3];
    const float* d    = (const float*)d_in[4];
    const float* gw   = (const float*)d_in[5];
    const float* gb   = (const float*)d_in[6];
    const float* dlru = (const float*)d_in[7];
    const float* dlrv = (const float*)d_in[8];
    float* out = (float*)d_out;

    char* ws = (char*)d_ws;
    unsigned short* ubf = (unsigned short*)ws;                       // 64 MiB
    unsigned short* wbf = (unsigned short*)(ws + (size_t)Mq * Dq * 2);  // 8 MiB
    float* psum  = (float*)(ws + (size_t)Mq * Dq * 2 + (size_t)Dq * Dq * 2);
    float* carry = psum  + (size_t)Bq * NC * Dq;                     // 1 MiB each
    float* deff  = carry + (size_t)Bq * NC * Dq;                     // 64 KB
    float* aat   = deff  + (size_t)Bq * Dq;
    float* aaLt  = aat   + Dq;

    k0_convert<<<2048, 256, 0, stream>>>(u, gw, a, ubf, wbf, aat, aaLt);

    dim3 g1(Dq / BNt, Mq / BMt);      // (16, 128)
    k1_gemm<<<g1, 256, 0, stream>>>(ubf, wbf, u, gb, out);

    dim3 g2(Dq / 512, NC, Bq);        // (4, 16, 8)
    k2_scanA<<<g2, 128, 0, stream>>>(out, aat, b, psum, carry);

    k3_deff<<<Bq, 256, 0, stream>>>(psum, d, dlru, dlrv, deff);

    k4_scanC<<<g2, 128, 0, stream>>>(out, aat, aaLt, b, c, deff, carry);
}

// Round 2
// 247.889 us; speedup vs baseline: 1.4492x; 1.4492x over previous
//
#include <hip/hip_runtime.h>
#include <hip/hip_bf16.h>
#include <math.h>

#define Bq 8
#define Tq 2048
#define Dq 2048
#define Rq 4
#define Mq (Bq*Tq)      // 16384
#define NC 16           // scan chunks
#define CL (Tq/NC)      // 128 timesteps per chunk

typedef __attribute__((ext_vector_type(8))) short bf16x8;
typedef __attribute__((ext_vector_type(4))) float f32x4;
typedef __attribute__((ext_vector_type(4))) unsigned short us4;

__device__ __forceinline__ unsigned short f2bf(float x) {
    unsigned int u = __float_as_uint(x);
    unsigned int r = (u + 0x7fffu + ((u >> 16) & 1u)) >> 16;   // RNE
    return (unsigned short)r;
}

// ---------------- K0: convert u, gate_w to bf16; build aa / aa^CL tables ----
__global__ __launch_bounds__(256) void k0_convert(
    const float* __restrict__ u, const float* __restrict__ gw,
    const float* __restrict__ a,
    unsigned short* __restrict__ ubf, unsigned short* __restrict__ wbf,
    float* __restrict__ aat, float* __restrict__ aaLt)
{
    const long long uN4 = (long long)Mq * Dq / 4;
    const long long wN4 = (long long)Dq * Dq / 4;
    long long gid = (long long)blockIdx.x * blockDim.x + threadIdx.x;
    if (gid < Dq) {
        float aa = tanhf(a[gid]);
        aat[gid] = aa;
        aaLt[gid] = exp2f((float)CL * log2f(aa));
    }
    long long stride = (long long)gridDim.x * blockDim.x;
    for (long long i = gid; i < uN4 + wN4; i += stride) {
        const float4* src; unsigned short* dst; long long j;
        if (i < uN4) { src = (const float4*)u;  dst = ubf; j = i; }
        else         { src = (const float4*)gw; dst = wbf; j = i - uN4; }
        float4 v = src[j];
        us4 p;
        p.x = f2bf(v.x); p.y = f2bf(v.y); p.z = f2bf(v.z); p.w = f2bf(v.w);
        *(us4*)(dst + j * 4) = p;
    }
}

// ---------------- K1: 256x256 8-phase bf16 MFMA GEMM + sigmoid epilogue -----
// BM=BN=256, BK=64, 512 thr = 8 waves (2M x 4N), per-wave out 128x64.
// LDS (ushort units): [dbuf:32768][A:0 / B:16384][half:8192][kslab:4096][row*32]
// st_16x32 swizzle: read idx ^= (rr&8)<<1; stage via source lane l^=(l>>4)&2.

#define PH_BAR __builtin_amdgcn_s_barrier()
#define PRIO1  __builtin_amdgcn_s_setprio(1)
#define PRIO0  __builtin_amdgcn_s_setprio(0)

#define LDA(CBASE, qb) do { _Pragma("unroll") for (int f_ = 0; f_ < 4; ++f_) { \
    _Pragma("unroll") for (int ks_ = 0; ks_ < 2; ++ks_) { \
        int r_ = ((qb) + f_) * 16 + rr; \
        int ix_ = (CBASE) + wr * 8192 + ks_ * 4096 + r_ * 32 + kb; \
        ix_ ^= (rr & 8) << 1; \
        aF[ks_][f_] = *(const bf16x8*)&lds[ix_]; } } } while (0)

#define LDB(CBASE, fnb) do { _Pragma("unroll") for (int f_ = 0; f_ < 2; ++f_) { \
    _Pragma("unroll") for (int ks_ = 0; ks_ < 2; ++ks_) { \
        int c_ = (wc & 1) * 64 + ((fnb) + f_) * 16 + rr; \
        int ix_ = (CBASE) + 16384 + (wc >> 1) * 8192 + ks_ * 4096 + c_ * 32 + kb; \
        ix_ ^= (rr & 8) << 1; \
        bF[ks_][(fnb) + f_] = *(const bf16x8*)&lds[ix_]; } } } while (0)

#define MMA(fmb, fnb) do { _Pragma("unroll") for (int fm_ = 0; fm_ < 4; ++fm_) \
    _Pragma("unroll") for (int fn_ = 0; fn_ < 2; ++fn_) \
    _Pragma("unroll") for (int ks_ = 0; ks_ < 2; ++ks_) \
        acc[(fmb) + fm_][(fnb) + fn_] = __builtin_amdgcn_mfma_f32_16x16x32_bf16( \
            aF[ks_][fm_], bF[ks_][(fnb) + fn_], acc[(fmb) + fm_][(fnb) + fn_], 0, 0, 0); } while (0)

#define STAGE(SRC, ROWBASE, OPB, DB, KT) do { _Pragma("unroll") for (int h_ = 0; h_ < 2; ++h_) { \
    _Pragma("unroll") for (int ks_ = 0; ks_ < 2; ++ks_) { \
        const unsigned short* g_ = (SRC) + (long long)((ROWBASE) + h_ * 128 + wave * 16 + srow) * Dq \
                                   + (KT) * 64 + ks_ * 32 + scol; \
        __builtin_amdgcn_global_load_lds( \
            (const __attribute__((address_space(1))) void*)g_, \
            (__attribute__((address_space(3))) void*)&lds[(DB) * 32768 + (OPB) + h_ * 8192 + ks_ * 4096 + wave * 512], \
            16, 0, 0); } } } while (0)

__global__ __launch_bounds__(512, 2) void k1_gemm(
    const unsigned short* __restrict__ Abf,   // u   [M][K] bf16
    const unsigned short* __restrict__ Bbf,   // gw  [N][K] bf16 (B^T layout)
    const float* __restrict__ gate_b,         // [D]
    float* __restrict__ ug)                   // out: u_g [M][D] f32 (= d_out)
{
    __shared__ unsigned short lds[65536];     // 128 KiB
    const int tid  = threadIdx.x;
    const int wave = tid >> 6, lane = tid & 63;
    const int wr = wave >> 2, wc = wave & 3;  // 2M x 4N waves

    // XCD-aware swizzle (nwg = 512, divisible by 8)
    const int bid = blockIdx.x;
    const int swz = (bid & 7) * 64 + (bid >> 3);
    const int tm = (swz >> 3) * 256;          // 64 m-blocks
    const int tn = (swz & 7) * 256;           // 8 n-blocks

    const int rr = lane & 15, kq = lane >> 4, kb = kq * 8;
    // stage source pre-swizzle lane
    const int lp = lane ^ ((lane >> 4) & 2);
    const int srow = lp >> 2;                 // row in 16-row subtile
    const int scol = (lp & 3) * 8;            // bf16 col in 32-col slab

    f32x4 acc[8][4] = {};
    bf16x8 aF[2][4], bF[2][4];

    // prologue: stage K-tiles 0 (buf0) and 1 (buf1)
    STAGE(Bbf, tn, 16384, 0, 0);
    STAGE(Abf, tm, 0,     0, 0);
    STAGE(Bbf, tn, 16384, 1, 1);
    STAGE(Abf, tm, 0,     1, 1);
    asm volatile("s_waitcnt vmcnt(8)" ::: "memory");
    PH_BAR;

    const int NIT = Dq / 128;                 // 16 iters, 2 K-tiles each
    for (int it = 0; it < NIT; ++it) {
        const int t2 = 2 * it + 2, t3 = 2 * it + 3;
        const bool pre = (it < NIT - 1);

        // ---- K-tile even (buf0) : phases 1-4 ----
        LDA(0, 0); LDB(0, 0);
        PH_BAR; PRIO1; MMA(0, 0); PRIO0; PH_BAR;
        LDB(0, 2);
        PH_BAR; PRIO1; MMA(0, 2); PRIO0; PH_BAR;
        LDA(0, 4);
        if (pre) STAGE(Bbf, tn, 16384, 0, t2);
        PH_BAR; PRIO1; MMA(4, 0); PRIO0; PH_BAR;
        if (pre) STAGE(Abf, tm, 0, 0, t2);
        PH_BAR;
        if (pre) asm volatile("s_waitcnt vmcnt(8)" ::: "memory");
        else     asm volatile("s_waitcnt vmcnt(0)" ::: "memory");
        PRIO1; MMA(4, 2); PRIO0; PH_BAR;

        // ---- K-tile odd (buf1) : phases 5-8 ----
        LDA(32768, 0); LDB(32768, 0);
        PH_BAR; PRIO1; MMA(0, 0); PRIO0; PH_BAR;
        LDB(32768, 2);
        PH_BAR; PRIO1; MMA(0, 2); PRIO0; PH_BAR;
        LDA(32768, 4);
        if (pre) STAGE(Bbf, tn, 16384, 1, t3);
        PH_BAR; PRIO1; MMA(4, 0); PRIO0; PH_BAR;
        if (pre) STAGE(Abf, tm, 0, 1, t3);
        PH_BAR;
        if (pre) asm volatile("s_waitcnt vmcnt(8)" ::: "memory");
        else     asm volatile("s_waitcnt vmcnt(0)" ::: "memory");
        PRIO1; MMA(4, 2); PRIO0; PH_BAR;
    }

    // epilogue: u_g = u * sigmoid(logit + gate_b), u read as bf16
#pragma unroll
    for (int fm = 0; fm < 8; ++fm) {
#pragma unroll
        for (int fn = 0; fn < 4; ++fn) {
            const int col = tn + wc * 64 + fn * 16 + rr;
            const float gb = gate_b[col];
#pragma unroll
            for (int j = 0; j < 4; ++j) {
                const int row = tm + wr * 128 + fm * 16 + kq * 4 + j;
                const long long idx = (long long)row * Dq + col;
                const float logit = acc[fm][fn][j] + gb;
                const float s = 1.0f / (1.0f + __expf(-logit));
                const float uv = __uint_as_float((unsigned)Abf[idx] << 16);
                ug[idx] = uv * s;
            }
        }
    }
}

// ---------------- K2: scan pass A — per-chunk local scan + partial sums -----
__global__ __launch_bounds__(128) void k2_scanA(
    const float* __restrict__ ug, const float* __restrict__ aat,
    const float* __restrict__ bvec,
    float* __restrict__ psum, float* __restrict__ carry)
{
    const int d0 = blockIdx.x * 512 + threadIdx.x * 4;
    const int ck = blockIdx.y, bb = blockIdx.z;
    f32x4 aa = *(const f32x4*)&aat[d0];
    f32x4 bv = *(const f32x4*)&bvec[d0];
    f32x4 s = {0.f, 0.f, 0.f, 0.f}, sum = {0.f, 0.f, 0.f, 0.f};
    const float* base = ug + ((long long)bb * Tq + (long long)ck * CL) * Dq + d0;
    for (int t = 0; t < CL; ++t) {
        f32x4 x = *(const f32x4*)(base + (long long)t * Dq);
        sum += x;
        s = aa * s + bv * x;
    }
    long long ci = ((long long)bb * NC + ck) * Dq + d0;
    *(f32x4*)&psum[ci]  = sum;
    *(f32x4*)&carry[ci] = s;
}

// ---------------- K3: mean -> rank-4 projection -> d_eff --------------------
__global__ __launch_bounds__(256) void k3_deff(
    const float* __restrict__ psum, const float* __restrict__ dvec,
    const float* __restrict__ dlru, const float* __restrict__ dlrv,
    float* __restrict__ deff)
{
    const int bb = blockIdx.x, tid = threadIdx.x;
    __shared__ float red[4][256];
    __shared__ float proj[4];
    float pr[4] = {0.f, 0.f, 0.f, 0.f};
    for (int i = 0; i < Dq / 256; ++i) {
        int dd = tid + i * 256;
        float m = 0.f;
        for (int k = 0; k < NC; ++k) m += psum[((long long)bb * NC + k) * Dq + dd];
        m *= (1.0f / (float)Tq);
#pragma unroll
        for (int r = 0; r < 4; ++r) pr[r] += m * dlru[dd * Rq + r];
    }
#pragma unroll
    for (int r = 0; r < 4; ++r) red[r][tid] = pr[r];
    __syncthreads();
    for (int off = 128; off > 0; off >>= 1) {
        if (tid < off)
#pragma unroll
            for (int r = 0; r < 4; ++r) red[r][tid] += red[r][tid + off];
        __syncthreads();
    }
    if (tid < 4) proj[tid] = red[tid][0] * 0.25f;
    __syncthreads();
    float p0 = proj[0], p1 = proj[1], p2 = proj[2], p3 = proj[3];
    for (int i = 0; i < Dq / 256; ++i) {
        int e = tid + i * 256;
        float v = dvec[e] + p0 * dlrv[0 * Dq + e] + p1 * dlrv[1 * Dq + e]
                          + p2 * dlrv[2 * Dq + e] + p3 * dlrv[3 * Dq + e];
        deff[(long long)bb * Dq + e] = v;
    }
}

// ---------------- K4: scan pass C — combine carries, rescan, write y --------
__global__ __launch_bounds__(128) void k4_scanC(
    float* __restrict__ ug,                   // in: u_g, out: y (in-place)
    const float* __restrict__ aat, const float* __restrict__ aaLt,
    const float* __restrict__ bvec, const float* __restrict__ cvec,
    const float* __restrict__ deff, const float* __restrict__ carry)
{
    const int d0 = blockIdx.x * 512 + threadIdx.x * 4;
    const int ck = blockIdx.y, bb = blockIdx.z;
    f32x4 aa  = *(const f32x4*)&aat[d0];
    f32x4 aaL = *(const f32x4*)&aaLt[d0];
    f32x4 bv  = *(const f32x4*)&bvec[d0];
    f32x4 cv  = *(const f32x4*)&cvec[d0];
    f32x4 de  = *(const f32x4*)&deff[(long long)bb * Dq + d0];
    f32x4 s = {0.f, 0.f, 0.f, 0.f};
    for (int j = 0; j < ck; ++j) {
        f32x4 cj = *(const f32x4*)&carry[((long long)bb * NC + j) * Dq + d0];
        s = aaL * s + cj;
    }
    float* base = ug + ((long long)bb * Tq + (long long)ck * CL) * Dq + d0;
    for (int t = 0; t < CL; ++t) {
        f32x4 x = *(const f32x4*)(base + (long long)t * Dq);
        s = aa * s + bv * x;
        f32x4 y = cv * s + de * x;
        *(f32x4*)(base + (long long)t * Dq) = y;
    }
}

extern "C" void kernel_launch(void* const* d_in, const int* in_sizes, int n_in,
                              void* d_out, int out_size, void* d_ws, size_t ws_size,
                              hipStream_t stream)
{
    const float* u    = (const float*)d_in[0];
    const float* a    = (const float*)d_in[1];
    const float* b    = (const float*)d_in[2];
    const float* c    = (const float*)d_in[3];
    const float* d    = (const float*)d_in[4];
    const float* gw   = (const float*)d_in[5];
    const float* gb   = (const float*)d_in[6];
    const float* dlru = (const float*)d_in[7];
    const float* dlrv = (const float*)d_in[8];
    float* out = (float*)d_out;

    char* ws = (char*)d_ws;
    unsigned short* ubf = (unsigned short*)ws;                          // 64 MiB
    unsigned short* wbf = (unsigned short*)(ws + (size_t)Mq * Dq * 2);  // 8 MiB
    float* psum  = (float*)(ws + (size_t)Mq * Dq * 2 + (size_t)Dq * Dq * 2);
    float* carry = psum  + (size_t)Bq * NC * Dq;
    float* deff  = carry + (size_t)Bq * NC * Dq;
    float* aat   = deff  + (size_t)Bq * Dq;
    float* aaLt  = aat   + Dq;

    k0_convert<<<2048, 256, 0, stream>>>(u, gw, a, ubf, wbf, aat, aaLt);

    k1_gemm<<<512, 512, 0, stream>>>(ubf, wbf, gb, out);

    dim3 g2(Dq / 512, NC, Bq);
    k2_scanA<<<g2, 128, 0, stream>>>(out, aat, b, psum, carry);

    k3_deff<<<Bq, 256, 0, stream>>>(psum, d, dlru, dlrv, deff);

    k4_scanC<<<g2, 128, 0, stream>>>(out, aat, aaLt, b, c, deff, carry);
}

// Round 3
// 229.418 us; speedup vs baseline: 1.5659x; 1.0805x over previous
//
#include <hip/hip_runtime.h>
#include <hip/hip_bf16.h>
#include <math.h>

#define Bq 8
#define Tq 2048
#define Dq 2048
#define Rq 4
#define Mq (Bq*Tq)      // 16384
#define NC 16           // scan chunks
#define CL (Tq/NC)      // 128 timesteps per chunk

typedef __attribute__((ext_vector_type(8))) short bf16x8;
typedef __attribute__((ext_vector_type(4))) float f32x4;
typedef __attribute__((ext_vector_type(4))) unsigned short us4;

__device__ __forceinline__ unsigned short f2bf(float x) {
    unsigned int u = __float_as_uint(x);
    unsigned int r = (u + 0x7fffu + ((u >> 16) & 1u)) >> 16;   // RNE
    return (unsigned short)r;
}
__device__ __forceinline__ float bf2f(unsigned short h) {
    return __uint_as_float((unsigned)h << 16);
}

template<int UGBF>
__device__ __forceinline__ f32x4 ld4(const void* p, long long off) {
    if constexpr (UGBF) {
        us4 v = *(const us4*)((const unsigned short*)p + off);
        f32x4 r;
        r.x = bf2f(v.x); r.y = bf2f(v.y); r.z = bf2f(v.z); r.w = bf2f(v.w);
        return r;
    } else {
        return *(const f32x4*)((const float*)p + off);
    }
}

// ---------------- K0: convert u, gate_w to bf16; build aa / aa^CL tables ----
__global__ __launch_bounds__(256) void k0_convert(
    const float* __restrict__ u, const float* __restrict__ gw,
    const float* __restrict__ a,
    unsigned short* __restrict__ ubf, unsigned short* __restrict__ wbf,
    float* __restrict__ aat, float* __restrict__ aaLt)
{
    const long long uN4 = (long long)Mq * Dq / 4;
    const long long wN4 = (long long)Dq * Dq / 4;
    long long gid = (long long)blockIdx.x * blockDim.x + threadIdx.x;
    if (gid < Dq) {
        float aa = tanhf(a[gid]);
        aat[gid] = aa;
        aaLt[gid] = exp2f((float)CL * log2f(aa));
    }
    long long stride = (long long)gridDim.x * blockDim.x;
    for (long long i = gid; i < uN4 + wN4; i += stride) {
        const float4* src; unsigned short* dst; long long j;
        if (i < uN4) { src = (const float4*)u;  dst = ubf; j = i; }
        else         { src = (const float4*)gw; dst = wbf; j = i - uN4; }
        float4 v = src[j];
        us4 p;
        p.x = f2bf(v.x); p.y = f2bf(v.y); p.z = f2bf(v.z); p.w = f2bf(v.w);
        *(us4*)(dst + j * 4) = p;
    }
}

// ---------------- K1: 256x256 8-phase bf16 MFMA GEMM + sigmoid epilogue -----
// BM=BN=256, BK=64, 512 thr = 8 waves (2M x 4N), per-wave out 128x64.
// LDS (ushort units): [dbuf:32768][A:0 / B:16384][half:8192][kslab:4096][row*32]
// st_16x32 swizzle hoisted into per-lane base regs: XOR bit4 is a function of
// rr*32+kb only; all fragment increments have no bits <9, so (X+Y)^16=(X^16)+Y.

#define PH_BAR __builtin_amdgcn_s_barrier()
#define PRIO1  __builtin_amdgcn_s_setprio(1)
#define PRIO0  __builtin_amdgcn_s_setprio(0)

#define LDA(BASE, qb) do { _Pragma("unroll") for (int f_ = 0; f_ < 4; ++f_) \
    { _Pragma("unroll") for (int ks_ = 0; ks_ < 2; ++ks_) \
        aF[ks_][f_] = *(const bf16x8*)&lds[(BASE) + ks_ * 4096 + ((qb) + f_) * 512]; } } while (0)

#define LDB(BASE, fnb) do { _Pragma("unroll") for (int f_ = 0; f_ < 2; ++f_) \
    { _Pragma("unroll") for (int ks_ = 0; ks_ < 2; ++ks_) \
        bF[ks_][(fnb) + f_] = *(const bf16x8*)&lds[(BASE) + ks_ * 4096 + ((fnb) + f_) * 512]; } } while (0)

#define MMA(fmb, fnb) do { _Pragma("unroll") for (int fm_ = 0; fm_ < 4; ++fm_) \
    _Pragma("unroll") for (int fn_ = 0; fn_ < 2; ++fn_) \
    _Pragma("unroll") for (int ks_ = 0; ks_ < 2; ++ks_) \
        acc[(fmb) + fm_][(fnb) + fn_] = __builtin_amdgcn_mfma_f32_16x16x32_bf16( \
            aF[ks_][fm_], bF[ks_][(fnb) + fn_], acc[(fmb) + fm_][(fnb) + fn_], 0, 0, 0); } while (0)

#define STAGE(G0, G1, OPB, DB, KOFF) do { _Pragma("unroll") for (int h_ = 0; h_ < 2; ++h_) { \
    const unsigned short* gp_ = h_ ? (G1) : (G0); \
    _Pragma("unroll") for (int ks_ = 0; ks_ < 2; ++ks_) { \
        __builtin_amdgcn_global_load_lds( \
            (const __attribute__((address_space(1))) void*)(gp_ + (KOFF) + ks_ * 32), \
            (__attribute__((address_space(3))) void*)&lds[(DB) * 32768 + (OPB) + h_ * 8192 + ks_ * 4096 + wave * 512], \
            16, 0, 0); } } } while (0)

template<int UGBF>
__global__ __launch_bounds__(512, 2) void k1_gemm(
    const unsigned short* __restrict__ Abf,   // u   [M][K] bf16
    const unsigned short* __restrict__ Bbf,   // gw  [N][K] bf16 (B^T layout)
    const float* __restrict__ gate_b,         // [D]
    void* __restrict__ ug_)                   // out: u_g [M][D] (f32 or bf16)
{
    __shared__ unsigned short lds[65536];     // 128 KiB
    const int tid  = threadIdx.x;
    const int wave = tid >> 6, lane = tid & 63;
    const int wr = wave >> 2, wc = wave & 3;  // 2M x 4N waves

    const int bid = blockIdx.x;
    const int swz = (bid & 7) * 64 + (bid >> 3);   // XCD swizzle, 512 % 8 == 0
    const int tm = (swz >> 3) * 256;
    const int tn = (swz & 7) * 256;

    const int rr = lane & 15, kq = lane >> 4, kb = kq * 8;
    const int lp = lane ^ ((lane >> 4) & 2);  // stage-source pre-swizzle lane
    const int srow = lp >> 2;
    const int scol = (lp & 3) * 8;

    // hoisted swizzled LDS read bases (ushort units)
    const int swA0 = (wr * 8192 + rr * 32 + kb) ^ ((rr & 8) << 1);
    const int swA1 = swA0 + 32768;
    const int swB0 = (16384 + (wc >> 1) * 8192 + (wc & 1) * 2048 + rr * 32 + kb) ^ ((rr & 8) << 1);
    const int swB1 = swB0 + 32768;

    // running stage pointers (element offset = current it*128)
    const unsigned short* gA0 = Abf + (long long)(tm + wave * 16 + srow) * Dq + scol;
    const unsigned short* gA1 = gA0 + 128 * Dq;
    const unsigned short* gB0 = Bbf + (long long)(tn + wave * 16 + srow) * Dq + scol;
    const unsigned short* gB1 = gB0 + 128 * Dq;

    f32x4 acc[8][4] = {};
    bf16x8 aF[2][4], bF[2][4];

    // prologue: stage K-tiles 0 (buf0) and 1 (buf1)
    STAGE(gB0, gB1, 16384, 0, 0);
    STAGE(gA0, gA1, 0,     0, 0);
    STAGE(gB0, gB1, 16384, 1, 64);
    STAGE(gA0, gA1, 0,     1, 64);
    asm volatile("s_waitcnt vmcnt(8)" ::: "memory");
    PH_BAR;

    const int NIT = Dq / 128;                 // 16 iters, 2 K-tiles each
    for (int it = 0; it < NIT; ++it) {
        const bool pre = (it < NIT - 1);

        // ---- K-tile even (buf0) : phases 1-4 ----
        LDA(swA0, 0); LDB(swB0, 0);
        PH_BAR; PRIO1; MMA(0, 0); PRIO0; PH_BAR;
        LDB(swB0, 2);
        PH_BAR; PRIO1; MMA(0, 2); PRIO0; PH_BAR;
        LDA(swA0, 4);
        if (pre) STAGE(gB0, gB1, 16384, 0, 128);
        PH_BAR; PRIO1; MMA(4, 0); PRIO0; PH_BAR;
        if (pre) STAGE(gA0, gA1, 0, 0, 128);
        PH_BAR;
        if (pre) asm volatile("s_waitcnt vmcnt(8)" ::: "memory");
        else     asm volatile("s_waitcnt vmcnt(0)" ::: "memory");
        PRIO1; MMA(4, 2); PRIO0; PH_BAR;

        // ---- K-tile odd (buf1) : phases 5-8 ----
        LDA(swA1, 0); LDB(swB1, 0);
        PH_BAR; PRIO1; MMA(0, 0); PRIO0; PH_BAR;
        LDB(swB1, 2);
        PH_BAR; PRIO1; MMA(0, 2); PRIO0; PH_BAR;
        LDA(swA1, 4);
        if (pre) STAGE(gB0, gB1, 16384, 1, 192);
        PH_BAR; PRIO1; MMA(4, 0); PRIO0; PH_BAR;
        if (pre) STAGE(gA0, gA1, 0, 1, 192);
        PH_BAR;
        if (pre) asm volatile("s_waitcnt vmcnt(8)" ::: "memory");
        else     asm volatile("s_waitcnt vmcnt(0)" ::: "memory");
        PRIO1; MMA(4, 2); PRIO0; PH_BAR;

        gA0 += 128; gA1 += 128; gB0 += 128; gB1 += 128;
    }

    // epilogue: u_g = u * sigmoid(logit + gate_b), u read as bf16
#pragma unroll
    for (int fm = 0; fm < 8; ++fm) {
#pragma unroll
        for (int fn = 0; fn < 4; ++fn) {
            const int col = tn + wc * 64 + fn * 16 + rr;
            const float gb = gate_b[col];
#pragma unroll
            for (int j = 0; j < 4; ++j) {
                const int row = tm + wr * 128 + fm * 16 + kq * 4 + j;
                const long long idx = (long long)row * Dq + col;
                const float logit = acc[fm][fn][j] + gb;
                const float s = 1.0f / (1.0f + __expf(-logit));
                const float uv = bf2f(Abf[idx]);
                if constexpr (UGBF) ((unsigned short*)ug_)[idx] = f2bf(uv * s);
                else                ((float*)ug_)[idx] = uv * s;
            }
        }
    }
}

// ---------------- K2: scan pass A — per-chunk local scan + partial sums -----
template<int UGBF>
__global__ __launch_bounds__(128) void k2_scanA(
    const void* __restrict__ ug, const float* __restrict__ aat,
    const float* __restrict__ bvec,
    float* __restrict__ psum, float* __restrict__ carry)
{
    const int d0 = blockIdx.x * 512 + threadIdx.x * 4;
    const int ck = blockIdx.y, bb = blockIdx.z;
    f32x4 aa = *(const f32x4*)&aat[d0];
    f32x4 bv = *(const f32x4*)&bvec[d0];
    f32x4 s = {0.f, 0.f, 0.f, 0.f}, sum = {0.f, 0.f, 0.f, 0.f};
    const long long base = ((long long)bb * Tq + (long long)ck * CL) * Dq + d0;
    for (int t = 0; t < CL; ++t) {
        f32x4 x = ld4<UGBF>(ug, base + (long long)t * Dq);
        sum += x;
        s = aa * s + bv * x;
    }
    long long ci = ((long long)bb * NC + ck) * Dq + d0;
    *(f32x4*)&psum[ci]  = sum;
    *(f32x4*)&carry[ci] = s;
}

// ---------------- K3: mean -> rank-4 projection -> d_eff --------------------
__global__ __launch_bounds__(256) void k3_deff(
    const float* __restrict__ psum, const float* __restrict__ dvec,
    const float* __restrict__ dlru, const float* __restrict__ dlrv,
    float* __restrict__ deff)
{
    const int bb = blockIdx.x, tid = threadIdx.x;
    __shared__ float red[4][256];
    __shared__ float proj[4];
    float pr[4] = {0.f, 0.f, 0.f, 0.f};
    for (int i = 0; i < Dq / 256; ++i) {
        int dd = tid + i * 256;
        float m = 0.f;
        for (int k = 0; k < NC; ++k) m += psum[((long long)bb * NC + k) * Dq + dd];
        m *= (1.0f / (float)Tq);
#pragma unroll
        for (int r = 0; r < 4; ++r) pr[r] += m * dlru[dd * Rq + r];
    }
#pragma unroll
    for (int r = 0; r < 4; ++r) red[r][tid] = pr[r];
    __syncthreads();
    for (int off = 128; off > 0; off >>= 1) {
        if (tid < off)
#pragma unroll
            for (int r = 0; r < 4; ++r) red[r][tid] += red[r][tid + off];
        __syncthreads();
    }
    if (tid < 4) proj[tid] = red[tid][0] * 0.25f;
    __syncthreads();
    float p0 = proj[0], p1 = proj[1], p2 = proj[2], p3 = proj[3];
    for (int i = 0; i < Dq / 256; ++i) {
        int e = tid + i * 256;
        float v = dvec[e] + p0 * dlrv[0 * Dq + e] + p1 * dlrv[1 * Dq + e]
                          + p2 * dlrv[2 * Dq + e] + p3 * dlrv[3 * Dq + e];
        deff[(long long)bb * Dq + e] = v;
    }
}

// ---------------- K4: scan pass C — combine carries, rescan, write y --------
template<int UGBF>
__global__ __launch_bounds__(128) void k4_scanC(
    const void* __restrict__ ug, float* __restrict__ yout,
    const float* __restrict__ aat, const float* __restrict__ aaLt,
    const float* __restrict__ bvec, const float* __restrict__ cvec,
    const float* __restrict__ deff, const float* __restrict__ carry)
{
    const int d0 = blockIdx.x * 512 + threadIdx.x * 4;
    const int ck = blockIdx.y, bb = blockIdx.z;
    f32x4 aa  = *(const f32x4*)&aat[d0];
    f32x4 aaL = *(const f32x4*)&aaLt[d0];
    f32x4 bv  = *(const f32x4*)&bvec[d0];
    f32x4 cv  = *(const f32x4*)&cvec[d0];
    f32x4 de  = *(const f32x4*)&deff[(long long)bb * Dq + d0];
    f32x4 s = {0.f, 0.f, 0.f, 0.f};
    for (int j = 0; j < ck; ++j) {
        f32x4 cj = *(const f32x4*)&carry[((long long)bb * NC + j) * Dq + d0];
        s = aaL * s + cj;
    }
    const long long base = ((long long)bb * Tq + (long long)ck * CL) * Dq + d0;
    for (int t = 0; t < CL; ++t) {
        f32x4 x = ld4<UGBF>(ug, base + (long long)t * Dq);
        s = aa * s + bv * x;
        f32x4 y = cv * s + de * x;
        *(f32x4*)&yout[base + (long long)t * Dq] = y;
    }
}

extern "C" void kernel_launch(void* const* d_in, const int* in_sizes, int n_in,
                              void* d_out, int out_size, void* d_ws, size_t ws_size,
                              hipStream_t stream)
{
    const float* u    = (const float*)d_in[0];
    const float* a    = (const float*)d_in[1];
    const float* b    = (const float*)d_in[2];
    const float* c    = (const float*)d_in[3];
    const float* d    = (const float*)d_in[4];
    const float* gw   = (const float*)d_in[5];
    const float* gb   = (const float*)d_in[6];
    const float* dlru = (const float*)d_in[7];
    const float* dlrv = (const float*)d_in[8];
    float* out = (float*)d_out;

    char* ws = (char*)d_ws;
    const size_t sz_ubf = (size_t)Mq * Dq * 2;          // 67108864
    const size_t sz_wbf = (size_t)Dq * Dq * 2;          // 8388608
    const size_t sz_ug  = (size_t)Mq * Dq * 2;          // bf16 u_g
    const size_t sz_ps  = (size_t)Bq * NC * Dq * 4;     // 2 MiB total (psum+carry)

    unsigned short* ubf = (unsigned short*)ws;
    unsigned short* wbf = (unsigned short*)(ws + sz_ubf);

    // bf16-u_g mode needs ubf+wbf+ugbf+psum+carry+deff+aat+aaLt
    const size_t need_bf16 = sz_ubf + sz_wbf + sz_ug + 2 * sz_ps
                           + (size_t)Bq * Dq * 4 + 2 * (size_t)Dq * 4;
    const bool ugbf_mode = (ws_size >= need_bf16);

    char* rest = ws + sz_ubf + sz_wbf;
    unsigned short* ugbf = (unsigned short*)rest;
    char* tail = ugbf_mode ? (rest + sz_ug) : rest;
    float* psum  = (float*)tail;
    float* carry = psum  + (size_t)Bq * NC * Dq;
    float* deff  = carry + (size_t)Bq * NC * Dq;
    float* aat   = deff  + (size_t)Bq * Dq;
    float* aaLt  = aat   + Dq;

    k0_convert<<<2048, 256, 0, stream>>>(u, gw, a, ubf, wbf, aat, aaLt);

    dim3 g2(Dq / 512, NC, Bq);
    if (ugbf_mode) {
        k1_gemm<1><<<512, 512, 0, stream>>>(ubf, wbf, gb, ugbf);
        k2_scanA<1><<<g2, 128, 0, stream>>>(ugbf, aat, b, psum, carry);
        k3_deff<<<Bq, 256, 0, stream>>>(psum, d, dlru, dlrv, deff);
        k4_scanC<1><<<g2, 128, 0, stream>>>(ugbf, out, aat, aaLt, b, c, deff, carry);
    } else {
        k1_gemm<0><<<512, 512, 0, stream>>>(ubf, wbf, gb, out);
        k2_scanA<0><<<g2, 128, 0, stream>>>(out, aat, b, psum, carry);
        k3_deff<<<Bq, 256, 0, stream>>>(psum, d, dlru, dlrv, deff);
        k4_scanC<0><<<g2, 128, 0, stream>>>(out, out, aat, aaLt, b, c, deff, carry);
    }
}